// Round 12
// baseline (607.595 us; speedup 1.0000x reference)
//
#include <hip/hip_runtime.h>

#define NB 32      // batch
#define NJ 8192    // h*w*Nin
#define NC 10      // NUM_CAPS
#define CL 16      // CAP_LEN
#define KK 160     // NC*CL
#define JT 16      // j per block
#define NTHR 640   // 40 k4 x 16 jj  (t = k4*16 + jj)
#define BCH 4      // batches per barrier pair
#define NPART (NJ / JT)   // 512 partial slots along j
#define EPSQ 1e-20f

// in-wave sum over jj = lane&15, pure VALU via DPP adds
template<int CTRL>
__device__ __forceinline__ float dpp_add(float v) {
    int s = __builtin_amdgcn_update_dpp(0, __float_as_int(v), CTRL, 0xF, 0xF, true);
    return v + __int_as_float(s);
}
__device__ __forceinline__ float red16(float v) {
    v = dpp_add<0xB1>(v);    // quad_perm xor1
    v = dpp_add<0x4E>(v);    // quad_perm xor2
    v = dpp_add<0x141>(v);   // row_half_mirror
    v = dpp_add<0x140>(v);   // row_mirror
    return v;
}

// ================= REAL PATH: round-4 proven kernels, verbatim =================
template<int R>
__global__ __launch_bounds__(NTHR, 5)
void rout_kernel(const float* __restrict__ x, const float* __restrict__ W,
                 const float* __restrict__ vsum, float* __restrict__ part) {
    __shared__ float xs[NB][JT][10];   // 20 KB
    __shared__ float vsl[NB][KK];      // 20 KB
    __shared__ float bl[BCH][JT][12];
    __shared__ float cl[BCH][JT][12];

    const int t   = threadIdx.x;
    const int jj  = t & 15;
    const int k4  = t >> 4;
    const int nB  = k4 >> 2;
    const int c4  = k4 & 3;
    const int j0  = blockIdx.x * JT;

    float4 w[8];
    {
        const float* wp = W + ((size_t)(j0 + jj) * 8) * KK + (k4 << 2);
        #pragma unroll
        for (int i = 0; i < 8; ++i)
            w[i] = *(const float4*)(wp + i * KK);
    }
    for (int e4 = t; e4 < NB * JT * 2; e4 += NTHR) {
        const int b = e4 >> 5, rem = e4 & 31, jx = rem >> 1, hf = rem & 1;
        const float4 v = *(const float4*)(x + ((size_t)b * NJ + j0 + jx) * 8 + hf * 4);
        float* d = &xs[b][jx][hf * 4];
        d[0] = v.x; d[1] = v.y; d[2] = v.z; d[3] = v.w;
    }
    if (R > 0) {
        for (int f4 = t; f4 < NB * 40; f4 += NTHR) {
            const int b = f4 / 40, rem = f4 % 40;
            *(float4*)&vsl[b][rem * 4] = *(const float4*)(vsum + (size_t)b * KK + rem * 4);
        }
    }
    __syncthreads();

    for (int b0 = 0; b0 < NB; b0 += BCH) {
        float4 u[BCH];
        #pragma unroll
        for (int bc = 0; bc < BCH; ++bc) {
            float4 acc = {0.f, 0.f, 0.f, 0.f};
            #pragma unroll
            for (int seg = 0; seg < 4; ++seg) {
                const float2 xv = *(const float2*)&xs[b0 + bc][jj][seg * 2];
                const float4 wa = w[seg * 2], wb = w[seg * 2 + 1];
                acc.x = fmaf(wa.x, xv.x, acc.x); acc.y = fmaf(wa.y, xv.x, acc.y);
                acc.z = fmaf(wa.z, xv.x, acc.z); acc.w = fmaf(wa.w, xv.x, acc.w);
                acc.x = fmaf(wb.x, xv.y, acc.x); acc.y = fmaf(wb.y, xv.y, acc.y);
                acc.z = fmaf(wb.z, xv.y, acc.z); acc.w = fmaf(wb.w, xv.y, acc.w);
            }
            u[bc] = acc;
        }

        if (R > 0) {
            #pragma unroll
            for (int bc = 0; bc < BCH; ++bc) {
                const float4 vv = *(const float4*)&vsl[b0 + bc][k4 * 4];
                float bd = u[bc].x * vv.x + u[bc].y * vv.y
                         + u[bc].z * vv.z + u[bc].w * vv.w;
                bd += __shfl_xor(bd, 16);
                bd += __shfl_xor(bd, 32);
                if (c4 == 0) bl[bc][jj][nB] = bd;
            }
            __syncthreads();
            {
                const int bcC = t / 160, rem = t % 160;
                const int jjC = rem & 15, nn = rem >> 4;
                float m = -1e30f;
                #pragma unroll
                for (int q = 0; q < NC; ++q) m = fmaxf(m, bl[bcC][jjC][q]);
                float sum = 0.f;
                #pragma unroll
                for (int q = 0; q < NC; ++q) sum += __expf(bl[bcC][jjC][q] - m);
                cl[bcC][jjC][nn] = __expf(bl[bcC][jjC][nn] - m) / sum;
            }
            __syncthreads();
        }

        #pragma unroll
        for (int bc = 0; bc < BCH; ++bc) {
            const int b = b0 + bc;
            const float c = (R == 0) ? 0.1f : cl[bc][jj][nB];
            const float sx = red16(u[bc].x * c);
            const float sy = red16(u[bc].y * c);
            const float sz = red16(u[bc].z * c);
            const float sw = red16(u[bc].w * c);
            if (jj == 0) {
                float4 q; q.x = sx; q.y = sy; q.z = sz; q.w = sw;
                *(float4*)(part + ((size_t)blockIdx.x * NB + b) * KK + (k4 << 2)) = q;
            }
        }
    }
}

template<int MODE>
__global__ __launch_bounds__(1024)
void reduce_squash(const float* __restrict__ part, const float* __restrict__ biases,
                   float* __restrict__ vsum, float* __restrict__ out) {
    __shared__ float4 red[16][64];
    const int t   = threadIdx.x;
    const int col = t & 63;
    const int pc  = t >> 6;
    const int g   = blockIdx.x * 64 + col;
    const float4* p4 = (const float4*)part;

    float4 acc = {0.f, 0.f, 0.f, 0.f};
    #pragma unroll 4
    for (int p = pc * 32; p < pc * 32 + 32; ++p) {
        const float4 v = p4[(size_t)p * (NB * KK / 4) + g];
        acc.x += v.x; acc.y += v.y; acc.z += v.z; acc.w += v.w;
    }
    red[pc][col] = acc;
    __syncthreads();
    if (pc == 0) {
        #pragma unroll
        for (int q = 1; q < 16; ++q) {
            const float4 v = red[q][col];
            acc.x += v.x; acc.y += v.y; acc.z += v.z; acc.w += v.w;
        }
        const int k4 = g % 40;
        const float4 bb = *(const float4*)(biases + k4 * 4);
        float4 v;
        {
            const float s0 = acc.x + bb.x, n0 = fabsf(s0);
            v.x = (n0 * n0) / (1.f + n0 * n0) / (n0 + EPSQ) * s0;
            const float s1 = acc.y + bb.y, n1 = fabsf(s1);
            v.y = (n1 * n1) / (1.f + n1 * n1) / (n1 + EPSQ) * s1;
            const float s2 = acc.z + bb.z, n2 = fabsf(s2);
            v.z = (n2 * n2) / (1.f + n2 * n2) / (n2 + EPSQ) * s2;
            const float s3 = acc.w + bb.w, n3 = fabsf(s3);
            v.w = (n3 * n3) / (1.f + n3 * n3) / (n3 + EPSQ) * s3;
        }
        if (MODE == 2) {
            ((float4*)out)[g] = v;
        } else if (MODE == 1) {
            float4 o = ((float4*)vsum)[g];
            o.x += v.x; o.y += v.y; o.z += v.z; o.w += v.w;
            ((float4*)vsum)[g] = o;
        } else {
            ((float4*)vsum)[g] = v;
        }
    }
}

// ============ INSTRUMENTATION (results discarded; removed next round) ============
// All mirror the real kernel's geometry, launch bounds, and 47104 B LDS.
// asm-volatile opacity per rep prevents hoisting/DCE (rule #17).

__device__ __forceinline__ void stage_x(const float* __restrict__ x,
                                        float (*xs)[JT][10], int j0, int t) {
    for (int e4 = t; e4 < NB * JT * 2; e4 += NTHR) {
        const int b = e4 >> 5, rem = e4 & 31, jx = rem >> 1, hf = rem & 1;
        const float4 v = *(const float4*)(x + ((size_t)b * NJ + j0 + jx) * 8 + hf * 4);
        float* d = &xs[b][jx][hf * 4];
        d[0] = v.x; d[1] = v.y; d[2] = v.z; d[3] = v.w;
    }
}
__device__ __forceinline__ void load_w(const float* __restrict__ wp, float4 (&w)[8]) {
    #pragma unroll
    for (int i = 0; i < 8; ++i) w[i] = *(const float4*)(wp + i * KK);
}
__device__ __forceinline__ void opaque_w(float4 (&w)[8]) {
    #pragma unroll
    for (int i = 0; i < 8; ++i)
        asm volatile("" : "+v"(w[i].x), "+v"(w[i].y), "+v"(w[i].z), "+v"(w[i].w));
}
__device__ __forceinline__ float4 chunk_A(const float2 (&xv)[4], const float4 (&w)[8]) {
    float4 acc = {0.f, 0.f, 0.f, 0.f};
    #pragma unroll
    for (int seg = 0; seg < 4; ++seg) {
        const float2 v = xv[seg];
        const float4 wa = w[seg * 2], wb = w[seg * 2 + 1];
        acc.x = fmaf(wa.x, v.x, acc.x); acc.y = fmaf(wa.y, v.x, acc.y);
        acc.z = fmaf(wa.z, v.x, acc.z); acc.w = fmaf(wa.w, v.x, acc.w);
        acc.x = fmaf(wb.x, v.y, acc.x); acc.y = fmaf(wb.y, v.y, acc.y);
        acc.z = fmaf(wb.z, v.y, acc.z); acc.w = fmaf(wb.w, v.y, acc.w);
    }
    return acc;
}

// prol x8: W->regs + x->LDS only. Measures prologue (L2-warm after rep 0).
__global__ __launch_bounds__(NTHR, 5)
void ablate_prol(const float* __restrict__ x, const float* __restrict__ W,
                 float* __restrict__ scr) {
    __shared__ float xs[NB][JT][10];
    __shared__ float pad_lds[6656];
    const int t = threadIdx.x, jj = t & 15, k4 = t >> 4, j0 = blockIdx.x * JT;
    if (t == NTHR) pad_lds[0] = 1.f;
    const float* wp0 = W + ((size_t)(j0 + jj) * 8) * KK + (k4 << 2);
    float keep = 0.f;
    for (int rep = 0; rep < 8; ++rep) {
        const float* wp = wp0;
        asm volatile("" : "+v"(wp));
        float4 w[8];
        load_w(wp, w);
        stage_x(x, xs, j0, t);
        __syncthreads();
        #pragma unroll
        for (int i = 0; i < 8; ++i) keep += w[i].x + w[i].y + w[i].z + w[i].w;
        keep += xs[t & 31][jj][k4 % 10];
        __syncthreads();
    }
    scr[(size_t)blockIdx.x * NTHR + t] = keep;
}

// pa x2: prologue + phase A (xs LDS reads + FMA). No D.
__global__ __launch_bounds__(NTHR, 5)
void ablate_pa(const float* __restrict__ x, const float* __restrict__ W,
               float* __restrict__ scr) {
    __shared__ float xs[NB][JT][10];
    __shared__ float pad_lds[6656];
    const int t = threadIdx.x, jj = t & 15, k4 = t >> 4, j0 = blockIdx.x * JT;
    if (t == NTHR) pad_lds[0] = 1.f;
    float4 w[8];
    load_w(W + ((size_t)(j0 + jj) * 8) * KK + (k4 << 2), w);
    stage_x(x, xs, j0, t);
    __syncthreads();
    float keep = 0.f;
    for (int rep = 0; rep < 2; ++rep) {
        int jj_r = jj;
        asm volatile("" : "+v"(jj_r));
        opaque_w(w);
        #pragma unroll 1
        for (int b0 = 0; b0 < NB; b0 += BCH) {
            #pragma unroll
            for (int bc = 0; bc < BCH; ++bc) {
                float2 xv[4];
                #pragma unroll
                for (int h = 0; h < 4; ++h)
                    xv[h] = *(const float2*)&xs[b0 + bc][jj_r][h * 2];
                float4 acc = chunk_A(xv, w);
                asm volatile("" :: "v"(acc.x), "v"(acc.y), "v"(acc.z), "v"(acc.w));
                keep += acc.x;
            }
        }
    }
    scr[(size_t)blockIdx.x * NTHR + t] = keep;
}

// pad x3: prologue + A + D(red16, keep-style). Non-pipelined baseline for pipe A/B.
__global__ __launch_bounds__(NTHR, 5)
void ablate_pad(const float* __restrict__ x, const float* __restrict__ W,
                float* __restrict__ scr) {
    __shared__ float xs[NB][JT][10];
    __shared__ float pad_lds[6656];
    const int t = threadIdx.x, jj = t & 15, k4 = t >> 4, j0 = blockIdx.x * JT;
    if (t == NTHR) pad_lds[0] = 1.f;
    float4 w[8];
    load_w(W + ((size_t)(j0 + jj) * 8) * KK + (k4 << 2), w);
    stage_x(x, xs, j0, t);
    __syncthreads();
    float keep = 0.f;
    for (int rep = 0; rep < 3; ++rep) {
        int jj_r = jj;
        asm volatile("" : "+v"(jj_r));
        opaque_w(w);
        #pragma unroll 1
        for (int b0 = 0; b0 < NB; b0 += BCH) {
            #pragma unroll
            for (int bc = 0; bc < BCH; ++bc) {
                float2 xv[4];
                #pragma unroll
                for (int h = 0; h < 4; ++h)
                    xv[h] = *(const float2*)&xs[b0 + bc][jj_r][h * 2];
                float4 acc = chunk_A(xv, w);
                keep += red16(acc.x * 0.1f) + red16(acc.y * 0.1f)
                      + red16(acc.z * 0.1f) + red16(acc.w * 0.1f);
            }
        }
    }
    scr[(size_t)blockIdx.x * NTHR + t] = keep;
}

// pipe x3: same work as pad, but x reads double-buffered one chunk ahead.
__device__ __forceinline__ void pipe_load(float2 (&dst)[BCH][4],
                                          const float (*xs)[JT][10], int b0, int jj) {
    #pragma unroll
    for (int bc = 0; bc < BCH; ++bc)
        #pragma unroll
        for (int h = 0; h < 4; ++h)
            dst[bc][h] = *(const float2*)&xs[b0 + bc][jj][h * 2];
}
__device__ __forceinline__ void pipe_chunk(const float2 (&xv)[BCH][4],
                                           const float4 (&w)[8], float& keep) {
    #pragma unroll
    for (int bc = 0; bc < BCH; ++bc) {
        float4 acc = chunk_A(xv[bc], w);
        keep += red16(acc.x * 0.1f) + red16(acc.y * 0.1f)
              + red16(acc.z * 0.1f) + red16(acc.w * 0.1f);
    }
}
__global__ __launch_bounds__(NTHR, 5)
void ablate_pipe(const float* __restrict__ x, const float* __restrict__ W,
                 float* __restrict__ scr) {
    __shared__ float xs[NB][JT][10];
    __shared__ float pad_lds[6656];
    const int t = threadIdx.x, jj = t & 15, k4 = t >> 4, j0 = blockIdx.x * JT;
    if (t == NTHR) pad_lds[0] = 1.f;
    float4 w[8];
    load_w(W + ((size_t)(j0 + jj) * 8) * KK + (k4 << 2), w);
    stage_x(x, xs, j0, t);
    __syncthreads();
    float keep = 0.f;
    for (int rep = 0; rep < 3; ++rep) {
        int jj_r = jj;
        asm volatile("" : "+v"(jj_r));
        opaque_w(w);
        float2 xa[BCH][4], xb[BCH][4];
        pipe_load(xa, xs, 0, jj_r);
        #pragma unroll 1
        for (int b0 = 0; b0 < NB; b0 += 2 * BCH) {
            pipe_load(xb, xs, b0 + BCH, jj_r);
            pipe_chunk(xa, w, keep);
            if (b0 + 2 * BCH < NB) pipe_load(xa, xs, b0 + 2 * BCH, jj_r);
            pipe_chunk(xb, w, keep);
        }
    }
    scr[(size_t)blockIdx.x * NTHR + t] = keep;
}

// paglob x2: phase A with x straight from global (no LDS staging at all).
__global__ __launch_bounds__(NTHR, 5)
void ablate_paglob(const float* __restrict__ x, const float* __restrict__ W,
                   float* __restrict__ scr) {
    __shared__ float pad_lds[11776];   // full 47104 B footprint parity
    const int t = threadIdx.x, jj = t & 15, k4 = t >> 4, j0 = blockIdx.x * JT;
    if (t == NTHR) pad_lds[0] = 1.f;
    float4 w[8];
    load_w(W + ((size_t)(j0 + jj) * 8) * KK + (k4 << 2), w);
    float keep = 0.f;
    for (int rep = 0; rep < 2; ++rep) {
        int jj_r = jj;
        asm volatile("" : "+v"(jj_r));
        opaque_w(w);
        #pragma unroll 1
        for (int b0 = 0; b0 < NB; b0 += BCH) {
            #pragma unroll
            for (int bc = 0; bc < BCH; ++bc) {
                const float* xg = x + ((size_t)(b0 + bc) * NJ + j0 + jj_r) * 8;
                float2 xv[4];
                #pragma unroll
                for (int h = 0; h < 4; ++h)
                    xv[h] = *(const float2*)(xg + h * 2);
                float4 acc = chunk_A(xv, w);
                asm volatile("" :: "v"(acc.x), "v"(acc.y), "v"(acc.z), "v"(acc.w));
                keep += acc.x;
            }
        }
    }
    scr[(size_t)blockIdx.x * NTHR + t] = keep;
}

extern "C" void kernel_launch(void* const* d_in, const int* in_sizes, int n_in,
                              void* d_out, int out_size, void* d_ws, size_t ws_size,
                              hipStream_t stream) {
    const float* x      = (const float*)d_in[0];
    const float* W      = (const float*)d_in[1];
    const float* biases = (const float*)d_in[2];
    float* out  = (float*)d_out;
    float* part = (float*)d_ws;                        // [NPART][NB*KK]
    float* vsum = part + (size_t)NPART * NB * KK;      // [NB*KK]
    float* scr  = vsum + NB * KK;                      // ablation scratch (1.3 MB)

    const dim3 grid(NJ / JT);   // 512

    // ---- real path (round-4 proven) ----
    rout_kernel<0><<<grid, NTHR, 0, stream>>>(x, W, nullptr, part);
    reduce_squash<0><<<20, 1024, 0, stream>>>(part, biases, vsum, out);
    rout_kernel<1><<<grid, NTHR, 0, stream>>>(x, W, vsum, part);
    reduce_squash<1><<<20, 1024, 0, stream>>>(part, biases, vsum, out);
    rout_kernel<2><<<grid, NTHR, 0, stream>>>(x, W, vsum, part);
    reduce_squash<2><<<20, 1024, 0, stream>>>(part, biases, vsum, out);

    // ---- instrumentation (dead scratch; deterministic; removed next round) ----
    const size_t need = ((size_t)NPART * NB * KK + NB * KK
                         + (size_t)512 * NTHR) * sizeof(float);
    if (ws_size >= need) {
        ablate_prol  <<<grid, NTHR, 0, stream>>>(x, W, scr);
        ablate_pa    <<<grid, NTHR, 0, stream>>>(x, W, scr);
        ablate_pad   <<<grid, NTHR, 0, stream>>>(x, W, scr);
        ablate_pipe  <<<grid, NTHR, 0, stream>>>(x, W, scr);
        ablate_paglob<<<grid, NTHR, 0, stream>>>(x, W, scr);
    }
}